// Round 1
// 99.030 us; speedup vs baseline: 1.7056x; 1.7056x over previous
//
#include <hip/hip_runtime.h>

// SpatialShiftConvBlock (B=8,T=64,N=21,C=128,F=256), ALL float32:
//   xs[b,t,n,c] = x[b,t,(n - c%21) mod 21, c]       (per-channel circular roll)
//   y  = xs @ W + b                                 (1x1 conv == GEMM K=128)
//   y  = (y - mean)*rsqrt(var + 1e-3)*gamma + beta  (BN training stats over B,T,N)
//   out = relu(y)
//
// R29: three-kernel plan.
//  k_zero : clear 512-float ws (sums/sumsq)
//  k_conv : conv with 4-channel register tiling (float4 W row reads), LDS slab
//           stored TRANSPOSED+DUPLICATED xsT[c][42] so the rotated reads are
//           consecutive floats (ds_read2 pairs, broadcast, conflict-free).
//           Rows split 6/5/5/5 across the 4 waves. Fused bias + per-block
//           channel partial sums -> 1 atomicAdd per channel per block.
//  k_bnapply : coalesced float4 streaming pass; each thread's channel quad is
//           fixed (4*(t&63)), so scale/bias computed once per thread from ws.

#define NPOS 21
#define CIN  128
#define FOUT 256
#define BT   512            // B*T
#define M_TOTAL 10752       // BT*NPOS
#define BN_EPS 1e-3f
#define LROW 42             // duplicated LDS row length (2*NPOS)

template<int NR>
__device__ __forceinline__ void conv_rows(const float* __restrict__ xsT,
                                          const float* __restrict__ W,
                                          const float* __restrict__ bias,
                                          float* __restrict__ yout,
                                          float* __restrict__ sumL,
                                          float* __restrict__ sqL,
                                          int r0, int fb, int r)
{
    float acc[NR][4];
    #pragma unroll
    for (int j = 0; j < NR; j++) {
        acc[j][0] = 0.0f; acc[j][1] = 0.0f; acc[j][2] = 0.0f; acc[j][3] = 0.0f;
    }

    const float* Wp   = W + fb;      // coalesced: lane reads 16B, wave reads 1KB row
    const float* xrow = xsT;         // advances LROW floats per c
    int start = r0;                  // (r0 - c%21) mod 21 ; decrements with wrap
    #pragma unroll 4
    for (int c = 0; c < CIN; c++) {
        const float4 wv = *(const float4*)Wp;
        float xv[NR];
        #pragma unroll
        for (int j = 0; j < NR; j++) xv[j] = xrow[start + j];   // consecutive -> ds_read2
        #pragma unroll
        for (int j = 0; j < NR; j++) {
            acc[j][0] = fmaf(xv[j], wv.x, acc[j][0]);
            acc[j][1] = fmaf(xv[j], wv.y, acc[j][1]);
            acc[j][2] = fmaf(xv[j], wv.z, acc[j][2]);
            acc[j][3] = fmaf(xv[j], wv.w, acc[j][3]);
        }
        Wp   += FOUT;
        xrow += LROW;
        start = (start == 0) ? (NPOS - 1) : (start - 1);
    }

    const float4 bv = *(const float4*)(bias + fb);
    float ls0 = 0.f, ls1 = 0.f, ls2 = 0.f, ls3 = 0.f;
    float lq0 = 0.f, lq1 = 0.f, lq2 = 0.f, lq3 = 0.f;
    #pragma unroll
    for (int j = 0; j < NR; j++) {
        float4 o;
        o.x = acc[j][0] + bv.x;
        o.y = acc[j][1] + bv.y;
        o.z = acc[j][2] + bv.z;
        o.w = acc[j][3] + bv.w;
        *(float4*)(yout + (size_t)(r0 + j) * FOUT + fb) = o;    // coalesced 1KB/row
        ls0 += o.x; lq0 += o.x * o.x;
        ls1 += o.y; lq1 += o.y * o.y;
        ls2 += o.z; lq2 += o.z * o.z;
        ls3 += o.w; lq3 += o.w * o.w;
    }
    *(float4*)(sumL + r * FOUT + fb) = make_float4(ls0, ls1, ls2, ls3);
    *(float4*)(sqL  + r * FOUT + fb) = make_float4(lq0, lq1, lq2, lq3);
}

__global__ __launch_bounds__(256) void k_conv(const float* __restrict__ x,
                                              const float* __restrict__ W,
                                              const float* __restrict__ bias,
                                              float* __restrict__ y,
                                              float* __restrict__ ws)
{
    __shared__ float xsT[CIN * LROW];      // 21 KB, transposed + duplicated
    __shared__ float sumL[4 * FOUT];       // 4 KB per-rgroup partial sums
    __shared__ float sqL[4 * FOUT];        // 4 KB

    const int bt = blockIdx.x;
    const int t  = threadIdx.x;
    const float* xin = x + (size_t)bt * (NPOS * CIN);
    for (int i = t; i < NPOS * CIN; i += 256) {
        float v = xin[i];                  // fully coalesced
        int n = i >> 7;                    // i = n*128 + c
        int c = i & (CIN - 1);
        xsT[c * LROW + n]        = v;
        xsT[c * LROW + n + NPOS] = v;      // duplicate: rotation never wraps
    }
    __syncthreads();

    const int r  = t >> 6;                 // wave id = row group
    const int fb = (t & 63) << 2;          // channel quad base
    float* yout = y + (size_t)bt * (NPOS * FOUT);
    if (r == 0)
        conv_rows<6>(xsT, W, bias, yout, sumL, sqL, 0, fb, 0);          // rows 0..5
    else
        conv_rows<5>(xsT, W, bias, yout, sumL, sqL, 5 * r + 1, fb, r);  // 6..10,11..15,16..20
    __syncthreads();

    // cross-wave reduce, one atomic per channel per block (512 adds/address total)
    const int ch = t;
    float s = sumL[ch] + sumL[FOUT + ch] + sumL[2 * FOUT + ch] + sumL[3 * FOUT + ch];
    float q = sqL[ch]  + sqL[FOUT + ch]  + sqL[2 * FOUT + ch]  + sqL[3 * FOUT + ch];
    atomicAdd(ws + ch, s);
    atomicAdd(ws + FOUT + ch, q);
}

__global__ void k_zero(float* __restrict__ ws)
{
    ws[blockIdx.x * 256 + threadIdx.x] = 0.0f;
}

#define BN_BLOCKS 1344      // 1344 * 512 float4 = 688128 = 10752*256/4 exactly

__global__ __launch_bounds__(256) void k_bnapply(float* __restrict__ y,
                                                 const float* __restrict__ ws,
                                                 const float* __restrict__ gamma,
                                                 const float* __restrict__ beta)
{
    const int t  = threadIdx.x;
    const int fb = (t & 63) << 2;          // this thread's fixed channel quad
    const float4 sm = *(const float4*)(ws + fb);
    const float4 sq = *(const float4*)(ws + FOUT + fb);
    const float4 gm = *(const float4*)(gamma + fb);
    const float4 be = *(const float4*)(beta + fb);
    const float invM = 1.0f / (float)M_TOTAL;

    float sc[4], bs[4];
    {
        float m0 = sm.x * invM, m1 = sm.y * invM, m2 = sm.z * invM, m3 = sm.w * invM;
        float v0 = fmaf(-m0, m0, sq.x * invM);
        float v1 = fmaf(-m1, m1, sq.y * invM);
        float v2 = fmaf(-m2, m2, sq.z * invM);
        float v3 = fmaf(-m3, m3, sq.w * invM);
        sc[0] = rsqrtf(v0 + BN_EPS) * gm.x;  bs[0] = be.x - m0 * sc[0];
        sc[1] = rsqrtf(v1 + BN_EPS) * gm.y;  bs[1] = be.y - m1 * sc[1];
        sc[2] = rsqrtf(v2 + BN_EPS) * gm.z;  bs[2] = be.z - m2 * sc[2];
        sc[3] = rsqrtf(v3 + BN_EPS) * gm.w;  bs[3] = be.w - m3 * sc[3];
    }

    float4* y4 = (float4*)y;
    #pragma unroll
    for (int it = 0; it < 2; it++) {
        int g = blockIdx.x * 512 + it * 256 + t;   // g%64 == t%64 -> quad matches fb
        float4 v = y4[g];
        v.x = fmaxf(fmaf(v.x, sc[0], bs[0]), 0.0f);
        v.y = fmaxf(fmaf(v.y, sc[1], bs[1]), 0.0f);
        v.z = fmaxf(fmaf(v.z, sc[2], bs[2]), 0.0f);
        v.w = fmaxf(fmaf(v.w, sc[3], bs[3]), 0.0f);
        y4[g] = v;
    }
}

// Template-named symbol kept defined (harness-compat; not launched).
extern "C" __global__ void SpatialShiftConvBlock_71923522339050_kernel() {}

extern "C" void kernel_launch(void* const* d_in, const int* in_sizes, int n_in,
                              void* d_out, int out_size, void* d_ws, size_t ws_size,
                              hipStream_t stream) {
    float* y  = (float*)d_out;             // FLOAT32 output
    float* ws = (float*)d_ws;              // 512 floats: [sum | sumsq]
    k_zero<<<2, 256, 0, stream>>>(ws);
    k_conv<<<BT, 256, 0, stream>>>((const float*)d_in[0], (const float*)d_in[1],
                                   (const float*)d_in[2], y, ws);
    k_bnapply<<<BN_BLOCKS, 256, 0, stream>>>(y, ws,
                                             (const float*)d_in[3], (const float*)d_in[4]);
}